// Round 11
// baseline (47.255 us; speedup 1.0000x reference)
//
#include <hip/hip_runtime.h>
#include <hip/hip_fp16.h>

// SSIM loss — round 11: load-front P2 with VGPR headroom.
// launch_bounds(256,5) -> 102-reg budget; all 12 float4 loads per item are
// hoisted into explicit locals (48 VGPR) so the L3-latency is paid once per
// item, not ~3x (r10 had VGPR=36 -> forced load serialization).
// Otherwise r10 structure: merged 4-half h-plane {(sa,sb),(qsum,sab)},
// stride-64 (512B) rows, P3 imm-offset ds_read_b64, tile 64x32, LDS 22KB.

#define IMGH 512
#define IMGW 512
#define TW 64
#define TH 32
#define HRR 42            // TH + 10 h-rows
#define C1F 1.0e-4f
#define C2F 9.0e-4f
#define GX 8
#define GY 16
#define GZ 48
#define NBLOCKS (GX * GY * GZ)   // 6144
#define NPIX (16 * 3 * 512 * 512)

// Gaussian weights, sigma=1.5, ws=11 (validated r1-r10).
#define W0 0.0010283818f
#define W1 0.0075987503f
#define W2 0.0360007547f
#define W3 0.1093606960f
#define W4 0.2130055367f
#define W5 0.2660117184f

struct alignas(8) H4 { __half2 ab; __half2 qc; };  // (sa,sb) , (saa+sbb, sab)

static __device__ __forceinline__ __half2 pkrtz(float a, float b) {
    auto r = __builtin_amdgcn_cvt_pkrtz(a, b);   // __fp16 ext_vector(2)
    return *reinterpret_cast<__half2*>(&r);
}

__global__ __launch_bounds__(256, 5)
void ssim_tile(const float* __restrict__ img1, const float* __restrict__ img2,
               float* __restrict__ partials) {
    __shared__ H4 sPm[HRR][64];             // 21,504 B, stride 512B
    __shared__ float wsum[4];

    const float W[11] = {W0, W1, W2, W3, W4, W5, W4, W3, W2, W1, W0};
    __half2 wsH[11];      // (W[i], W[i])
#pragma unroll
    for (int i = 0; i < 11; ++i) wsH[i] = __half2half2(__float2half(W[i]));

    const int tid = threadIdx.x;
    const int r0 = blockIdx.y * TH;
    const int c0 = blockIdx.x * TW;
    const size_t pbase = (size_t)blockIdx.z * (IMGH * IMGW);
    const float* a0 = img1 + pbase;
    const float* b0 = img2 + pbase;
    const bool fast = (blockIdx.x >= 1) & (blockIdx.x <= GX - 2) &
                      (blockIdx.y >= 1) & (blockIdx.y <= GY - 2);

    // ---- Phase 2: horizontal conv, 8 out cols per item, 336 items ----
    auto h_item = [&](int idx) {
        const int row = idx >> 3;
        const int cg  = idx & 7;
        const int gr  = r0 - 5 + row;
        const bool rowok = (unsigned)gr < IMGH;
        const int grc = rowok ? gr : 0;
        const int gc0 = c0 + 8 * cg - 8;       // local col d <-> global gc0+d
        const float* ra = a0 + (size_t)grc * IMGW;
        const float* rb = b0 + (size_t)grc * IMGW;

        // --- load front: all 12 float4 in flight before any conversion ---
        float4 va[6], vb[6];
        if (fast) {
#pragma unroll
            for (int g = 0; g < 6; ++g)
                va[g] = *reinterpret_cast<const float4*>(ra + (gc0 + 4 * g));
#pragma unroll
            for (int g = 0; g < 6; ++g)
                vb[g] = *reinterpret_cast<const float4*>(rb + (gc0 + 4 * g));
        } else {
#pragma unroll
            for (int g = 0; g < 6; ++g) {
                int gc = gc0 + 4 * g;
                va[g] = make_float4(0.f, 0.f, 0.f, 0.f); vb[g] = va[g];
                if (rowok && (unsigned)gc < IMGW) {
                    va[g] = *reinterpret_cast<const float4*>(ra + gc);
                    vb[g] = *reinterpret_cast<const float4*>(rb + gc);
                }
            }
        }

        // --- convert: AB/QC built once per px ---
        __half2 AB[18], QC[18];
        auto emit = [&](int t, float a, float b) {
            AB[t] = pkrtz(a, b);
            QC[t] = pkrtz(__builtin_fmaf(a, a, b * b), a * b);
        };
        emit(0, va[0].w, vb[0].w);
#pragma unroll
        for (int g = 1; g < 6; ++g) {
            int t = 4 * g - 3;
            emit(t,     va[g].x, vb[g].x);
            emit(t + 1, va[g].y, vb[g].y);
            emit(t + 2, va[g].z, vb[g].z);
            if (g < 5) emit(t + 3, va[g].w, vb[g].w);
        }

        // --- pure packed-f16 conv core: 176 hfma2 ---
        __half2 accAB[8], accQC[8];
        const __half2 z2 = __half2half2(__float2half(0.f));
#pragma unroll
        for (int m = 0; m < 8; ++m) { accAB[m] = z2; accQC[m] = z2; }
#pragma unroll
        for (int t = 0; t < 18; ++t) {
#pragma unroll
            for (int m = 0; m < 8; ++m) {
                int k = t - m;
                if (k >= 0 && k <= 10) {
                    accAB[m] = __hfma2(wsH[k], AB[t], accAB[m]);
                    accQC[m] = __hfma2(wsH[k], QC[t], accQC[m]);
                }
            }
        }
#pragma unroll
        for (int m = 0; m < 8; ++m) {
            H4 h; h.ab = accAB[m]; h.qc = accQC[m];
            sPm[row][8 * cg + m] = h;
        }
    };
    h_item(tid);
    if (tid < HRR * 8 - 256) h_item(tid + 256);   // 80 extra items
    __syncthreads();

    // ---- Phase 3: vertical conv, 1 col x 8 rows per thread ----
    const int col = tid & 63;
    const int rbase = (tid >> 6) * 8;      // out rows rbase..rbase+7
    const H4* pm = &sPm[rbase][col];

    H4 hbuf[18];
#pragma unroll
    for (int j = 0; j < 18; ++j) hbuf[j] = pm[j * 64];   // imm offset j*512B

    __half2 mAB[8], mQC[8];
    {
        const __half2 z2 = __half2half2(__float2half(0.f));
#pragma unroll
        for (int r = 0; r < 8; ++r) { mAB[r] = z2; mQC[r] = z2; }
    }
#pragma unroll
    for (int j = 0; j < 18; ++j) {
#pragma unroll
        for (int r = 0; r < 8; ++r) {
            int i = j - r;
            if (i >= 0 && i <= 10) {
                mAB[r] = __hfma2(wsH[i], hbuf[j].ab, mAB[r]);
                mQC[r] = __hfma2(wsH[i], hbuf[j].qc, mQC[r]);
            }
        }
    }

    float lsum = 0.f;
#pragma unroll
    for (int r = 0; r < 8; ++r) {
        float2 m12 = __half22float2(mAB[r]);
        float2 qc  = __half22float2(mQC[r]);   // (E[aa]+E[bb], E[ab])
        float mu1 = m12.x, mu2 = m12.y;
        float mu11 = mu1 * mu1, mu22 = mu2 * mu2, mu12 = mu1 * mu2;
        float s12 = qc.y - mu12;
        float num = (2.f * mu12 + C1F) * (2.f * s12 + C2F);
        float den = (mu11 + mu22 + C1F) * ((qc.x - mu11 - mu22) + C2F);
        lsum += num * __builtin_amdgcn_rcpf(den);
    }

    // ---- Deterministic block reduction ----
#pragma unroll
    for (int off = 32; off > 0; off >>= 1) lsum += __shfl_down(lsum, off, 64);
    if ((tid & 63) == 0) wsum[tid >> 6] = lsum;
    __syncthreads();
    if (tid == 0) {
        float t = wsum[0] + wsum[1] + wsum[2] + wsum[3];
        partials[((size_t)blockIdx.z * GY + blockIdx.y) * GX + blockIdx.x] = t;
    }
}

__global__ __launch_bounds__(1024)
void ssim_reduce(const float* __restrict__ partials, float* __restrict__ out, int n) {
    __shared__ float lds[1024];
    float s = 0.f;
    for (int i = threadIdx.x; i < n; i += 1024) s += partials[i];
    lds[threadIdx.x] = s;
    __syncthreads();
    for (int off = 512; off > 0; off >>= 1) {
        if ((int)threadIdx.x < off) lds[threadIdx.x] += lds[threadIdx.x + off];
        __syncthreads();
    }
    if (threadIdx.x == 0) out[0] = 1.f - lds[0] / (float)NPIX;
}

extern "C" void kernel_launch(void* const* d_in, const int* in_sizes, int n_in,
                              void* d_out, int out_size, void* d_ws, size_t ws_size,
                              hipStream_t stream) {
    const float* img1 = (const float*)d_in[0];
    const float* img2 = (const float*)d_in[1];
    float* out = (float*)d_out;
    float* partials = (float*)d_ws;

    dim3 grid(GX, GY, GZ);
    ssim_tile<<<grid, 256, 0, stream>>>(img1, img2, partials);
    ssim_reduce<<<1, 1024, 0, stream>>>(partials, out, NBLOCKS);
}

// Round 12
// 45.231 us; speedup vs baseline: 1.0448x; 1.0448x over previous
//
#include <hip/hip_runtime.h>
#include <hip/hip_fp16.h>

// SSIM loss — round 12: 512-thread blocks, perfectly balanced P2.
// P2: 336 items (42 rows x 8 col-groups), one per thread (threads 336-511
// park at the barrier — cheap). Critical path = 1 load+compute item, not 2.
// P3: 1 col x 4 rows/thread (2048 px / 512). LDS 22KB -> 4 blocks/CU
// = 32 waves/CU = 100% static occupancy ceiling.
// Core: merged 4-half h-plane {(sa,sb),(qsum,sab)}, stride-64 (512B) rows,
// f16 packed conv math, direct-from-global P2 loads (L3-resident).

#define IMGH 512
#define IMGW 512
#define TW 64
#define TH 32
#define HRR 42            // TH + 10 h-rows
#define C1F 1.0e-4f
#define C2F 9.0e-4f
#define GX 8
#define GY 16
#define GZ 48
#define NBLOCKS (GX * GY * GZ)   // 6144
#define NPIX (16 * 3 * 512 * 512)

// Gaussian weights, sigma=1.5, ws=11 (validated r1-r11).
#define W0 0.0010283818f
#define W1 0.0075987503f
#define W2 0.0360007547f
#define W3 0.1093606960f
#define W4 0.2130055367f
#define W5 0.2660117184f

struct alignas(8) H4 { __half2 ab; __half2 qc; };  // (sa,sb) , (saa+sbb, sab)

static __device__ __forceinline__ __half2 pkrtz(float a, float b) {
    auto r = __builtin_amdgcn_cvt_pkrtz(a, b);   // __fp16 ext_vector(2)
    return *reinterpret_cast<__half2*>(&r);
}

__global__ __launch_bounds__(512, 4)
void ssim_tile(const float* __restrict__ img1, const float* __restrict__ img2,
               float* __restrict__ partials) {
    __shared__ H4 sPm[HRR][64];             // 21,504 B, stride 512B
    __shared__ float wsum[8];

    const float W[11] = {W0, W1, W2, W3, W4, W5, W4, W3, W2, W1, W0};
    __half2 wsH[11];      // (W[i], W[i])
#pragma unroll
    for (int i = 0; i < 11; ++i) wsH[i] = __half2half2(__float2half(W[i]));

    const int tid = threadIdx.x;
    const int r0 = blockIdx.y * TH;
    const int c0 = blockIdx.x * TW;
    const size_t pbase = (size_t)blockIdx.z * (IMGH * IMGW);
    const float* a0 = img1 + pbase;
    const float* b0 = img2 + pbase;
    const bool fast = (blockIdx.x >= 1) & (blockIdx.x <= GX - 2) &
                      (blockIdx.y >= 1) & (blockIdx.y <= GY - 2);

    // ---- Phase 2: horizontal conv, 8 out cols per item, 1 item/thread ----
    if (tid < HRR * 8) {
        const int row = tid >> 3;
        const int cg  = tid & 7;
        const int gr  = r0 - 5 + row;
        const bool rowok = (unsigned)gr < IMGH;
        const int grc = rowok ? gr : 0;
        const int gc0 = c0 + 8 * cg - 8;       // local col d <-> global gc0+d
        const float* ra = a0 + (size_t)grc * IMGW;
        const float* rb = b0 + (size_t)grc * IMGW;

        float4 va[6], vb[6];
        if (fast) {
#pragma unroll
            for (int g = 0; g < 6; ++g)
                va[g] = *reinterpret_cast<const float4*>(ra + (gc0 + 4 * g));
#pragma unroll
            for (int g = 0; g < 6; ++g)
                vb[g] = *reinterpret_cast<const float4*>(rb + (gc0 + 4 * g));
        } else {
#pragma unroll
            for (int g = 0; g < 6; ++g) {
                int gc = gc0 + 4 * g;
                va[g] = make_float4(0.f, 0.f, 0.f, 0.f); vb[g] = va[g];
                if (rowok && (unsigned)gc < IMGW) {
                    va[g] = *reinterpret_cast<const float4*>(ra + gc);
                    vb[g] = *reinterpret_cast<const float4*>(rb + gc);
                }
            }
        }

        __half2 AB[18], QC[18];
        auto emit = [&](int t, float a, float b) {
            AB[t] = pkrtz(a, b);
            QC[t] = pkrtz(__builtin_fmaf(a, a, b * b), a * b);
        };
        emit(0, va[0].w, vb[0].w);
#pragma unroll
        for (int g = 1; g < 6; ++g) {
            int t = 4 * g - 3;
            emit(t,     va[g].x, vb[g].x);
            emit(t + 1, va[g].y, vb[g].y);
            emit(t + 2, va[g].z, vb[g].z);
            if (g < 5) emit(t + 3, va[g].w, vb[g].w);
        }

        __half2 accAB[8], accQC[8];
        const __half2 z2 = __half2half2(__float2half(0.f));
#pragma unroll
        for (int m = 0; m < 8; ++m) { accAB[m] = z2; accQC[m] = z2; }
#pragma unroll
        for (int t = 0; t < 18; ++t) {
#pragma unroll
            for (int m = 0; m < 8; ++m) {
                int k = t - m;
                if (k >= 0 && k <= 10) {
                    accAB[m] = __hfma2(wsH[k], AB[t], accAB[m]);
                    accQC[m] = __hfma2(wsH[k], QC[t], accQC[m]);
                }
            }
        }
#pragma unroll
        for (int m = 0; m < 8; ++m) {
            H4 h; h.ab = accAB[m]; h.qc = accQC[m];
            sPm[row][8 * cg + m] = h;
        }
    }
    __syncthreads();

    // ---- Phase 3: vertical conv, 1 col x 4 rows per thread ----
    const int col = tid & 63;
    const int rbase = (tid >> 6) * 4;      // 0,4,...,28 ; out rows rbase..+3
    const H4* pm = &sPm[rbase][col];

    __half2 mAB[4], mQC[4];
    {
        const __half2 z2 = __half2half2(__float2half(0.f));
#pragma unroll
        for (int r = 0; r < 4; ++r) { mAB[r] = z2; mQC[r] = z2; }
    }
#pragma unroll
    for (int j = 0; j < 14; ++j) {
        H4 h = pm[j * 64];                 // imm offset j*512B
#pragma unroll
        for (int r = 0; r < 4; ++r) {
            int i = j - r;
            if (i >= 0 && i <= 10) {
                mAB[r] = __hfma2(wsH[i], h.ab, mAB[r]);
                mQC[r] = __hfma2(wsH[i], h.qc, mQC[r]);
            }
        }
    }

    float lsum = 0.f;
#pragma unroll
    for (int r = 0; r < 4; ++r) {
        float2 m12 = __half22float2(mAB[r]);
        float2 qc  = __half22float2(mQC[r]);   // (E[aa]+E[bb], E[ab])
        float mu1 = m12.x, mu2 = m12.y;
        float mu11 = mu1 * mu1, mu22 = mu2 * mu2, mu12 = mu1 * mu2;
        float s12 = qc.y - mu12;
        float num = (2.f * mu12 + C1F) * (2.f * s12 + C2F);
        float den = (mu11 + mu22 + C1F) * ((qc.x - mu11 - mu22) + C2F);
        lsum += num * __builtin_amdgcn_rcpf(den);
    }

    // ---- Deterministic block reduction (8 waves) ----
#pragma unroll
    for (int off = 32; off > 0; off >>= 1) lsum += __shfl_down(lsum, off, 64);
    if ((tid & 63) == 0) wsum[tid >> 6] = lsum;
    __syncthreads();
    if (tid == 0) {
        float t = 0.f;
#pragma unroll
        for (int w = 0; w < 8; ++w) t += wsum[w];
        partials[((size_t)blockIdx.z * GY + blockIdx.y) * GX + blockIdx.x] = t;
    }
}

__global__ __launch_bounds__(1024)
void ssim_reduce(const float* __restrict__ partials, float* __restrict__ out, int n) {
    __shared__ float lds[1024];
    float s = 0.f;
    for (int i = threadIdx.x; i < n; i += 1024) s += partials[i];
    lds[threadIdx.x] = s;
    __syncthreads();
    for (int off = 512; off > 0; off >>= 1) {
        if ((int)threadIdx.x < off) lds[threadIdx.x] += lds[threadIdx.x + off];
        __syncthreads();
    }
    if (threadIdx.x == 0) out[0] = 1.f - lds[0] / (float)NPIX;
}

extern "C" void kernel_launch(void* const* d_in, const int* in_sizes, int n_in,
                              void* d_out, int out_size, void* d_ws, size_t ws_size,
                              hipStream_t stream) {
    const float* img1 = (const float*)d_in[0];
    const float* img2 = (const float*)d_in[1];
    float* out = (float*)d_out;
    float* partials = (float*)d_ws;

    dim3 grid(GX, GY, GZ);
    ssim_tile<<<grid, 512, 0, stream>>>(img1, img2, partials);
    ssim_reduce<<<1, 1024, 0, stream>>>(partials, out, NBLOCKS);
}